// Round 12
// baseline (250.793 us; speedup 1.0000x reference)
//
#include <hip/hip_runtime.h>

// H2G2: 2-layer RGCN (R=4, per-relation mean) + mean-pool + linear.
// R1->R2: atomic scatter -> CSR gather. R2->R3: atomic pool -> segmented pool+cls.
// R3->R4: fp32 LDS GEMM -> bf16 MFMA. R4->R5: CSR via 2-level bucket sort.
// R5->R7: aggregate-then-transform; K=320 MFMA. R8 FAILED (LDS-Y occupancy cap).
// R10: register-resident Y fusion, 227us. R11 FAILED: masked-FMA rel-select
//   quadrupled per-edge VALU (50us/layer). REVERTED accumulate to R10's.
// R12: uniform padded CSR. Each node's 4 relation segments padded to
//   plen=max_r cnt_r with dummy edges -> zero row at index N (L1-hot).
//   Gather = single uniform loop, 4 edges (1/rel) x (1 eidx + 2 row loads)
//   = 12 independent loads in flight/iter; trip count max-of-16 plen (~10)
//   vs R10's sum-of-4-maxes (~36). No intra-node divergence.

#define RR 4
#define HH 64
#define KK 320         // (RR+1)*HH
#define LWN (HH * KK)  // weights per layer = 20480
#define EPB 4096       // edges per binning block
#define SBUF_D 6144    // per-bucket staging cap

using frag_ab = __attribute__((ext_vector_type(8))) short;
using frag_cd = __attribute__((ext_vector_type(4))) float;

__device__ inline short f2bf(float f) {
    unsigned u = __builtin_bit_cast(unsigned, f);
    unsigned r = u + 0x7fffu + ((u >> 16) & 1u);  // RNE
    return (short)(r >> 16);
}
__device__ inline float bf2f(short s) {
    unsigned u = ((unsigned)(unsigned short)s) << 16;
    return __builtin_bit_cast(float, u);
}

// ---- prep: fused init-independent work, partitioned by blockIdx ----
__global__ __launch_bounds__(256) void prep_kernel(
    const int* __restrict__ dst, int E, int NBUCK, int* __restrict__ bcnt,
    const float* __restrict__ basis1, const float* __restrict__ comp1, const float* __restrict__ root1,
    const float* __restrict__ basis2, const float* __restrict__ comp2, const float* __restrict__ root2,
    short* __restrict__ W1t, short* __restrict__ W2t,
    const int* __restrict__ batch, int* __restrict__ gstart, int N, int G,
    const float* __restrict__ x, short* __restrict__ Xb, short* __restrict__ H1,
    int ebl, int wbl, int nb) {
    const int bid = blockIdx.x;
    const int t = threadIdx.x;
    if (bid < ebl) {  // ---- histogram of dst>>8 ----
        __shared__ int lc[256];
        lc[t] = 0;
        __syncthreads();
        int e0 = bid * EPB, e1 = min(e0 + EPB, E);
        for (int e = e0 + t; e < e1; e += 256) atomicAdd(&lc[dst[e] >> 8], 1);
        __syncthreads();
        if (t < NBUCK && lc[t]) atomicAdd(&bcnt[t], lc[t]);
    } else if (bid < ebl + wbl) {  // ---- weights: Wt[c*320+k] = Wstack[k][c] ----
        int w = (bid - ebl) * 256 + t;
        int layer = w / LWN;
        int rem = w - layer * LWN;
        int c = rem / KK;
        int k = rem - c * KK;
        const float* basis = layer ? basis2 : basis1;
        const float* comp  = layer ? comp2  : comp1;
        const float* root  = layer ? root2  : root1;
        short* Wt          = layer ? W2t    : W1t;
        float v;
        if (k < HH) {
            v = root[k * HH + c];
        } else {
            int r = (k >> 6) - 1, kk = k & 63;
            v = 0.f;
#pragma unroll
            for (int b = 0; b < RR; ++b) v += comp[r * RR + b] * basis[(b * HH + kk) * HH + c];
        }
        Wt[c * KK + k] = f2bf(v);
    } else if (bid < ebl + wbl + nb) {  // ---- gstart ----
        int i = (bid - ebl - wbl) * 256 + t;
        if (i < N) {
            int b1 = batch[i];
            int b0 = (i == 0) ? -1 : batch[i - 1];
            for (int g = b0 + 1; g <= b1; ++g) gstart[g] = i;
            if (i == N - 1)
                for (int g = b1 + 1; g <= G; ++g) gstart[g] = N;
        }
    } else {  // ---- convert x fp32 -> bf16; zero row N of Xb and H1 ----
        int i4 = (bid - ebl - wbl - nb) * 256 + t;
        int base = i4 * 4;
        if (base < N * 64) {
            float4 f = *(const float4*)&x[base];
            short4 s;
            s.x = f2bf(f.x); s.y = f2bf(f.y); s.z = f2bf(f.z); s.w = f2bf(f.w);
            *(short4*)&Xb[base] = s;
        } else if (base < (N + 1) * 64) {
            short4 z = make_short4(0, 0, 0, 0);
            *(short4*)&Xb[base] = z;
            *(short4*)&H1[base] = z;
        }
    }
}

// ---- bin: block-local counting sort by bucket; packed payload src:16|et:2|dl:8 ----
__global__ __launch_bounds__(256) void bin_kernel(const int* __restrict__ src,
                                                  const int* __restrict__ dst,
                                                  const int* __restrict__ et,
                                                  const int* __restrict__ bcnt,
                                                  int* __restrict__ cur0,
                                                  int* __restrict__ tmp, int E) {
    __shared__ int lc[256];
    __shared__ int lscan[257];
    __shared__ int lbase[256];
    __shared__ int ss[256];
    __shared__ int sbuf[EPB];
    int t = threadIdx.x;
    int bv = bcnt[t];
    ss[t] = bv;
    __syncthreads();
#pragma unroll
    for (int off = 1; off < 256; off <<= 1) {
        int u = (t >= off) ? ss[t - off] : 0;
        __syncthreads();
        ss[t] += u;
        __syncthreads();
    }
    int boff_t = ss[t] - bv;
    lc[t] = 0;
    __syncthreads();
    int e0 = blockIdx.x * EPB;
    int e1 = min(e0 + EPB, E);
    for (int e = e0 + t; e < e1; e += 256) atomicAdd(&lc[dst[e] >> 8], 1);
    __syncthreads();
    int v = lc[t];
    ss[t] = v;
    __syncthreads();
#pragma unroll
    for (int off = 1; off < 256; off <<= 1) {
        int u = (t >= off) ? ss[t - off] : 0;
        __syncthreads();
        ss[t] += u;
        __syncthreads();
    }
    lscan[t] = ss[t] - v;
    if (t == 255) lscan[256] = ss[255];
    if (v) lbase[t] = boff_t + atomicAdd(&cur0[t], v);
    lc[t] = 0;
    __syncthreads();
    for (int e = e0 + t; e < e1; e += 256) {
        int d = dst[e];
        int b = d >> 8;
        int p = (src[e] << 10) | (et[e] << 8) | (d & 255);
        int pos = lscan[b] + atomicAdd(&lc[b], 1);
        sbuf[pos] = p;
    }
    __syncthreads();
    int tot = lscan[256];
    for (int i = t; i < tot; i += 256) {
        int lo = 0, hi = 255;
        while (lo < hi) { int mid = (lo + hi + 1) >> 1; if (lscan[mid] <= i) lo = mid; else hi = mid - 1; }
        tmp[lbase[lo] + (i - lscan[lo])] = sbuf[i];
    }
}

// ---- csr: per-bucket finalize: p_ptr/plen (padded uniform segments), inv,
//      eidx_pad with 4 equal-length relation segments (dummy = node N) ----
__global__ __launch_bounds__(256) void csr_kernel(const int* __restrict__ tmp,
                                                  const int* __restrict__ bcnt,
                                                  int* __restrict__ p_ptr,
                                                  int* __restrict__ plen,
                                                  int* __restrict__ eidx_pad,
                                                  float* __restrict__ inv,
                                                  int* __restrict__ gcur, int N) {
    __shared__ int cnt4l[1024];   // counts -> cursors
    __shared__ int segst[1024];   // initial (dl,r) start offsets (bucket-relative)
    __shared__ int dscan[256];
    __shared__ int ss[256];
    __shared__ int sb[SBUF_D];
    __shared__ int s0s, s1s, baseS;
    int b = blockIdx.x, t = threadIdx.x;
    int bv = bcnt[t];
    ss[t] = bv;
    __syncthreads();
#pragma unroll
    for (int off = 1; off < 256; off <<= 1) {
        int u = (t >= off) ? ss[t - off] : 0;
        __syncthreads();
        ss[t] += u;
        __syncthreads();
    }
    if (t == b) { s0s = ss[t] - bv; s1s = ss[t]; }
    __syncthreads();
    int s0 = s0s, s1 = s1s;
    int len = s1 - s0;
    for (int i = t; i < 1024; i += 256) cnt4l[i] = 0;
    __syncthreads();
    for (int i = s0 + t; i < s1; i += 256) {
        int e = tmp[i];
        atomicAdd(&cnt4l[((e & 255) << 2) | ((e >> 8) & 3)], 1);
    }
    __syncthreads();
    int c0 = cnt4l[t * 4], c1 = cnt4l[t * 4 + 1], c2 = cnt4l[t * 4 + 2], c3 = cnt4l[t * 4 + 3];
    int deg = c0 + c1 + c2 + c3;
    ss[t] = deg;
    __syncthreads();
#pragma unroll
    for (int off = 1; off < 256; off <<= 1) {
        int u = (t >= off) ? ss[t - off] : 0;
        __syncthreads();
        ss[t] += u;
        __syncthreads();
    }
    dscan[t] = ss[t] - deg;
    __syncthreads();
    // padded allocation: 4*pl per node, block-atomic on global cursor
    int pl = max(max(c0, c1), max(c2, c3));
    int fourpl = pl * 4;
    ss[t] = fourpl;
    __syncthreads();
#pragma unroll
    for (int off = 1; off < 256; off <<= 1) {
        int u = (t >= off) ? ss[t - off] : 0;
        __syncthreads();
        ss[t] += u;
        __syncthreads();
    }
    if (t == 255) baseS = atomicAdd(gcur, ss[255]);
    __syncthreads();
    int gbase = baseS + ss[t] - fourpl;
    int d0 = b << 8;
    int d = d0 + t;
    if (d < N) {
        p_ptr[d] = gbase;
        plen[d] = pl;
        inv[d * 4 + 0] = 1.0f / fmaxf((float)c0, 1.0f);
        inv[d * 4 + 1] = 1.0f / fmaxf((float)c1, 1.0f);
        inv[d * 4 + 2] = 1.0f / fmaxf((float)c2, 1.0f);
        inv[d * 4 + 3] = 1.0f / fmaxf((float)c3, 1.0f);
    }
    // staging cursors (bucket-relative) + saved starts
    int dbase = dscan[t];
    segst[t * 4]     = dbase;
    segst[t * 4 + 1] = dbase + c0;
    segst[t * 4 + 2] = dbase + c0 + c1;
    segst[t * 4 + 3] = dbase + c0 + c1 + c2;
    cnt4l[t * 4]     = segst[t * 4];
    cnt4l[t * 4 + 1] = segst[t * 4 + 1];
    cnt4l[t * 4 + 2] = segst[t * 4 + 2];
    cnt4l[t * 4 + 3] = segst[t * 4 + 3];
    __syncthreads();
    if (len <= SBUF_D) {
        for (int i = s0 + t; i < s1; i += 256) {
            int e = tmp[i];
            int key = ((e & 255) << 2) | ((e >> 8) & 3);
            int pos = atomicAdd(&cnt4l[key], 1);
            sb[pos] = ((e >> 10) << 2) | ((e >> 8) & 3);  // (src<<2)|et
        }
        __syncthreads();
        // thread t writes node t's padded segments
        if (d < N && pl > 0) {
            int cs[4] = {c0, c1, c2, c3};
#pragma unroll
            for (int r = 0; r < 4; ++r) {
                int st = segst[t * 4 + r];
                for (int j = 0; j < pl; ++j)
                    eidx_pad[gbase + r * pl + j] = (j < cs[r]) ? sb[st + j] : ((N << 2) | r);
            }
        }
    } else {  // improbable fallback: dummies first, then scatter real edges
        if (d < N && pl > 0)
#pragma unroll
            for (int r = 0; r < 4; ++r)
                for (int j = 0; j < pl; ++j)
                    eidx_pad[gbase + r * pl + j] = (N << 2) | r;
        __syncthreads();
        for (int i = s0 + t; i < s1; i += 256) {
            int e = tmp[i];
            int dl = e & 255;
            int r = (e >> 8) & 3;
            int key = (dl << 2) | r;
            int pos = atomicAdd(&cnt4l[key], 1);
            int joff = pos - segst[key];
            eidx_pad[p_ptr[d0 + dl] + r * plen[d0 + dl] + joff] = ((e >> 10) << 2) | r;
        }
    }
}

// ---- fused layer: register-resident Y; uniform padded gather: per iteration
// 4 edges (one per relation) = 12 independent loads in flight ----
__global__ __launch_bounds__(256) void layer_kernel(const int* __restrict__ p_ptr,
                                                    const int* __restrict__ plen,
                                                    const int* __restrict__ eidx,
                                                    const short* __restrict__ Xb,
                                                    const float* __restrict__ inv,
                                                    const short* __restrict__ Wt,
                                                    const float* __restrict__ bias,
                                                    short* __restrict__ out, int n) {
    const int t = threadIdx.x;
    const int wv = t >> 6;
    const int l = t & 63;
    const int m = l & 15;
    const int quad = l >> 4;
    const int node = blockIdx.x * 64 + wv * 16 + m;
    const bool valid = node < n;

    float accL[4][8], accH[4][8];
#pragma unroll
    for (int r = 0; r < 4; ++r)
#pragma unroll
        for (int j = 0; j < 8; ++j) { accL[r][j] = 0.f; accH[r][j] = 0.f; }

    int pp = 0, pl = 0;
    float4 iv = make_float4(0.f, 0.f, 0.f, 0.f);
    if (valid) {
        pp = p_ptr[node];
        pl = plen[node];
        iv = *(const float4*)&inv[node * 4];
    }
    const short* xbq = Xb + quad * 8;

    for (int j = 0; j < pl; ++j) {
        int p0 = eidx[pp + j];
        int p1 = eidx[pp + pl + j];
        int p2 = eidx[pp + 2 * pl + j];
        int p3 = eidx[pp + 3 * pl + j];
        const short* q0 = xbq + (size_t)(p0 >> 2) * 64;
        const short* q1 = xbq + (size_t)(p1 >> 2) * 64;
        const short* q2 = xbq + (size_t)(p2 >> 2) * 64;
        const short* q3 = xbq + (size_t)(p3 >> 2) * 64;
        frag_ab x0l = *(const frag_ab*)q0, x0h = *(const frag_ab*)(q0 + 32);
        frag_ab x1l = *(const frag_ab*)q1, x1h = *(const frag_ab*)(q1 + 32);
        frag_ab x2l = *(const frag_ab*)q2, x2h = *(const frag_ab*)(q2 + 32);
        frag_ab x3l = *(const frag_ab*)q3, x3h = *(const frag_ab*)(q3 + 32);
#pragma unroll
        for (int jj = 0; jj < 8; ++jj) {
            accL[0][jj] += bf2f(x0l[jj]); accH[0][jj] += bf2f(x0h[jj]);
            accL[1][jj] += bf2f(x1l[jj]); accH[1][jj] += bf2f(x1h[jj]);
            accL[2][jj] += bf2f(x2l[jj]); accH[2][jj] += bf2f(x2h[jj]);
            accL[3][jj] += bf2f(x3l[jj]); accH[3][jj] += bf2f(x3h[jj]);
        }
    }

    // build A-frags: a[0..1] = X row; a[2+2r], a[3+2r] = Y_r * inv_r
    frag_ab a[10];
#pragma unroll
    for (int f = 0; f < 10; ++f) a[f] = frag_ab{};
    if (valid) {
        const short* xr = Xb + (size_t)node * 64 + quad * 8;
        a[0] = *(const frag_ab*)xr;
        a[1] = *(const frag_ab*)(xr + 32);
    }
    {
        float s0 = iv.x, s1 = iv.y, s2 = iv.z, s3 = iv.w;
#pragma unroll
        for (int j = 0; j < 8; ++j) {
            a[2][j] = f2bf(accL[0][j] * s0); a[3][j] = f2bf(accH[0][j] * s0);
            a[4][j] = f2bf(accL[1][j] * s1); a[5][j] = f2bf(accH[1][j] * s1);
            a[6][j] = f2bf(accL[2][j] * s2); a[7][j] = f2bf(accH[2][j] * s2);
            a[8][j] = f2bf(accL[3][j] * s3); a[9][j] = f2bf(accH[3][j] * s3);
        }
    }

    const int nrow_base = blockIdx.x * 64 + wv * 16 + quad * 4;
#pragma unroll
    for (int ct = 0; ct < 4; ++ct) {
        const short* bp = Wt + (size_t)(ct * 16 + m) * KK + quad * 8;
        frag_cd acc = {0.f, 0.f, 0.f, 0.f};
#pragma unroll
        for (int f = 0; f < 10; ++f) {
            frag_ab bf = *(const frag_ab*)(bp + f * 32);
            acc = __builtin_amdgcn_mfma_f32_16x16x32_bf16(a[f], bf, acc, 0, 0, 0);
        }
        int col = ct * 16 + m;
        float bv = bias[col];
#pragma unroll
        for (int r = 0; r < 4; ++r) {
            int nr = nrow_base + r;
            if (nr < n) out[(size_t)nr * 64 + col] = f2bf(fmaxf(acc[r] + bv, 0.f));
        }
    }
}

// ---- pool (segmented) + classifier ----
__global__ __launch_bounds__(256) void pool_cls_kernel(const short* __restrict__ h2,
                                                       const int* __restrict__ gstart,
                                                       const float* __restrict__ w,
                                                       const float* __restrict__ b,
                                                       float* __restrict__ out) {
    __shared__ float red[4][64];
    const int g = blockIdx.x;
    const int t = threadIdx.x;
    const int h = t & 63;
    const int wv = t >> 6;
    const int s = gstart[g], e = gstart[g + 1];

    float acc = 0.f;
    for (int i = s + wv; i < e; i += 4) acc += bf2f(h2[(size_t)i * 64 + h]);
    red[wv][h] = acc;
    __syncthreads();
    if (wv == 0) {
        float sum = red[0][h] + red[1][h] + red[2][h] + red[3][h];
        red[0][h] = sum / fmaxf((float)(e - s), 1.0f);
    }
    __syncthreads();
    if (t < 4) {
        float sres = 0.f;
#pragma unroll 8
        for (int hh = 0; hh < 64; ++hh) sres += red[0][hh] * w[hh * 4 + t];
        out[g * 4 + t] = sres + b[t];
    }
}

extern "C" void kernel_launch(void* const* d_in, const int* in_sizes, int n_in,
                              void* d_out, int out_size, void* d_ws, size_t ws_size,
                              hipStream_t stream) {
    const float* x        = (const float*)d_in[0];
    const int* edge_index = (const int*)d_in[1];
    const int* edge_type  = (const int*)d_in[2];
    const int* batch      = (const int*)d_in[3];
    const float* basis1 = (const float*)d_in[4];
    const float* comp1  = (const float*)d_in[5];
    const float* root1  = (const float*)d_in[6];
    const float* bias1  = (const float*)d_in[7];
    const float* basis2 = (const float*)d_in[8];
    const float* comp2  = (const float*)d_in[9];
    const float* root2  = (const float*)d_in[10];
    const float* bias2  = (const float*)d_in[11];
    const float* clas_w = (const float*)d_in[12];
    const float* clas_b = (const float*)d_in[13];

    const int N = in_sizes[0] / 64;
    const int E = in_sizes[2];
    const int G = out_size / 4;
    const int* src = edge_index;
    const int* dst = edge_index + E;
    const int NBUCK = (N + 255) >> 8;

    char* base = (char*)d_ws;
    size_t off = 0;
    auto carve = [&](size_t bytes) { void* p = base + off; off = (off + bytes + 15) & ~(size_t)15; return p; };
    int*   bcnt    = (int*)carve(sizeof(int) * 256);
    int*   cur0    = (int*)carve(sizeof(int) * 256);
    int*   gcur    = (int*)carve(sizeof(int) * 256);   // [0] used; padded region
    int*   p_ptr   = (int*)carve(sizeof(int) * (size_t)N);
    int*   plen    = (int*)carve(sizeof(int) * (size_t)N);
    int*   gstart  = (int*)carve(sizeof(int) * ((size_t)G + 1));
    int*   tmp     = (int*)carve(sizeof(int) * (size_t)E);
    int*   eidx    = (int*)carve(sizeof(int) * ((size_t)E * 4 + (size_t)N * 8));
    float* inv     = (float*)carve(sizeof(float) * (size_t)N * RR);
    short* W1t     = (short*)carve(sizeof(short) * LWN);
    short* W2t     = (short*)carve(sizeof(short) * LWN);
    short* Xb1     = (short*)carve(sizeof(short) * ((size_t)N + 1) * 64);
    short* H1      = (short*)carve(sizeof(short) * ((size_t)N + 1) * 64);
    short* H2      = (short*)carve(sizeof(short) * (size_t)N * 64);

    const int nb  = (N + 255) / 256;
    const int ebl = (E + EPB - 1) / EPB;
    const int wbl = (2 * LWN + 255) / 256;
    const int cvb = (((N + 1) * 64 / 4) + 255) / 256;
    const int prep_blocks = ebl + wbl + nb + cvb;

    hipMemsetAsync(bcnt, 0, sizeof(int) * 768, stream);  // bcnt + cur0 + gcur

    prep_kernel<<<prep_blocks, 256, 0, stream>>>(
        dst, E, NBUCK, bcnt,
        basis1, comp1, root1, basis2, comp2, root2, W1t, W2t,
        batch, gstart, N, G, x, Xb1, H1, ebl, wbl, nb);
    bin_kernel<<<ebl, 256, 0, stream>>>(src, dst, edge_type, bcnt, cur0, tmp, E);
    csr_kernel<<<NBUCK, 256, 0, stream>>>(tmp, bcnt, p_ptr, plen, eidx, inv, gcur, N);

    const int layer_blocks = (N + 63) / 64;

    layer_kernel<<<layer_blocks, 256, 0, stream>>>(p_ptr, plen, eidx, Xb1, inv, W1t, bias1, H1, N);
    layer_kernel<<<layer_blocks, 256, 0, stream>>>(p_ptr, plen, eidx, H1, inv, W2t, bias2, H2, N);

    pool_cls_kernel<<<G, 256, 0, stream>>>(H2, gstart, clas_w, clas_b, (float*)d_out);
}

// Round 13
// 229.119 us; speedup vs baseline: 1.0946x; 1.0946x over previous
//
#include <hip/hip_runtime.h>

// H2G2: 2-layer RGCN (R=4, per-relation mean) + mean-pool + linear.
// R1->R2: atomic scatter -> CSR gather. R2->R3: atomic pool -> segmented pool+cls.
// R3->R4: fp32 LDS GEMM -> bf16 MFMA. R4->R5: CSR via 2-level bucket sort.
// R5->R7: aggregate-then-transform; K=320 MFMA. R8 FAILED (33.8KB LDS-Y occupancy cap).
// R10: register-resident Y fusion = 227us best. R11 FAILED (masked-FMA VALU bloat).
// R12 FAILED (padded CSR: +fetch, no gain). Root cause of layer plateau: only
//   3125 waves (1 per 16 nodes) = 23% occupancy ceiling; gather is latency-bound.
// R13: 2-wave cooperative gather. Block=128thr=2 waves/group -> 6250 waves (2x).
//   Each wave gathers half of each rel segment; wave1 ships partials via 8KB
//   LDS (frag-major, conflict-free) and exits; wave0 sums, scales, MFMAs.

#define RR 4
#define HH 64
#define KK 320         // (RR+1)*HH
#define LWN (HH * KK)  // weights per layer = 20480
#define EPB 4096       // edges per binning block
#define SBUF_D 6144    // per-bucket staging cap

using frag_ab = __attribute__((ext_vector_type(8))) short;
using frag_cd = __attribute__((ext_vector_type(4))) float;

__device__ inline short f2bf(float f) {
    unsigned u = __builtin_bit_cast(unsigned, f);
    unsigned r = u + 0x7fffu + ((u >> 16) & 1u);  // RNE
    return (short)(r >> 16);
}
__device__ inline float bf2f(short s) {
    unsigned u = ((unsigned)(unsigned short)s) << 16;
    return __builtin_bit_cast(float, u);
}

// ---- prep: fused init-independent work, partitioned by blockIdx ----
__global__ __launch_bounds__(256) void prep_kernel(
    const int* __restrict__ dst, int E, int NBUCK, int* __restrict__ bcnt,
    const float* __restrict__ basis1, const float* __restrict__ comp1, const float* __restrict__ root1,
    const float* __restrict__ basis2, const float* __restrict__ comp2, const float* __restrict__ root2,
    short* __restrict__ W1t, short* __restrict__ W2t,
    const int* __restrict__ batch, int* __restrict__ gstart, int N, int G,
    int* __restrict__ row_ptr,
    const float* __restrict__ x, short* __restrict__ Xb,
    int ebl, int wbl, int nb) {
    const int bid = blockIdx.x;
    const int t = threadIdx.x;
    if (bid < ebl) {  // ---- histogram of dst>>8 ----
        __shared__ int lc[256];
        lc[t] = 0;
        __syncthreads();
        int e0 = bid * EPB, e1 = min(e0 + EPB, E);
        for (int e = e0 + t; e < e1; e += 256) atomicAdd(&lc[dst[e] >> 8], 1);
        __syncthreads();
        if (t < NBUCK && lc[t]) atomicAdd(&bcnt[t], lc[t]);
    } else if (bid < ebl + wbl) {  // ---- weights: Wt[c*320+k] = Wstack[k][c] ----
        int w = (bid - ebl) * 256 + t;
        int layer = w / LWN;
        int rem = w - layer * LWN;
        int c = rem / KK;
        int k = rem - c * KK;
        const float* basis = layer ? basis2 : basis1;
        const float* comp  = layer ? comp2  : comp1;
        const float* root  = layer ? root2  : root1;
        short* Wt          = layer ? W2t    : W1t;
        float v;
        if (k < HH) {
            v = root[k * HH + c];
        } else {
            int r = (k >> 6) - 1, kk = k & 63;
            v = 0.f;
#pragma unroll
            for (int b = 0; b < RR; ++b) v += comp[r * RR + b] * basis[(b * HH + kk) * HH + c];
        }
        Wt[c * KK + k] = f2bf(v);
    } else if (bid < ebl + wbl + nb) {  // ---- gstart + row_ptr sentinel ----
        int i = (bid - ebl - wbl) * 256 + t;
        if (i == 0) row_ptr[N] = E;
        if (i < N) {
            int b1 = batch[i];
            int b0 = (i == 0) ? -1 : batch[i - 1];
            for (int g = b0 + 1; g <= b1; ++g) gstart[g] = i;
            if (i == N - 1)
                for (int g = b1 + 1; g <= G; ++g) gstart[g] = N;
        }
    } else {  // ---- convert x fp32 -> bf16 ----
        int i4 = (bid - ebl - wbl - nb) * 256 + t;
        int base = i4 * 4;
        if (base < N * 64) {
            float4 f = *(const float4*)&x[base];
            short4 s;
            s.x = f2bf(f.x); s.y = f2bf(f.y); s.z = f2bf(f.z); s.w = f2bf(f.w);
            *(short4*)&Xb[base] = s;
        }
    }
}

// ---- bin: block-local counting sort by bucket; packed payload src:16|et:2|dl:8 ----
__global__ __launch_bounds__(256) void bin_kernel(const int* __restrict__ src,
                                                  const int* __restrict__ dst,
                                                  const int* __restrict__ et,
                                                  const int* __restrict__ bcnt,
                                                  int* __restrict__ cur0,
                                                  int* __restrict__ tmp, int E) {
    __shared__ int lc[256];
    __shared__ int lscan[257];
    __shared__ int lbase[256];
    __shared__ int ss[256];
    __shared__ int sbuf[EPB];
    int t = threadIdx.x;
    int bv = bcnt[t];
    ss[t] = bv;
    __syncthreads();
#pragma unroll
    for (int off = 1; off < 256; off <<= 1) {
        int u = (t >= off) ? ss[t - off] : 0;
        __syncthreads();
        ss[t] += u;
        __syncthreads();
    }
    int boff_t = ss[t] - bv;
    lc[t] = 0;
    __syncthreads();
    int e0 = blockIdx.x * EPB;
    int e1 = min(e0 + EPB, E);
    for (int e = e0 + t; e < e1; e += 256) atomicAdd(&lc[dst[e] >> 8], 1);
    __syncthreads();
    int v = lc[t];
    ss[t] = v;
    __syncthreads();
#pragma unroll
    for (int off = 1; off < 256; off <<= 1) {
        int u = (t >= off) ? ss[t - off] : 0;
        __syncthreads();
        ss[t] += u;
        __syncthreads();
    }
    lscan[t] = ss[t] - v;
    if (t == 255) lscan[256] = ss[255];
    if (v) lbase[t] = boff_t + atomicAdd(&cur0[t], v);
    lc[t] = 0;
    __syncthreads();
    for (int e = e0 + t; e < e1; e += 256) {
        int d = dst[e];
        int b = d >> 8;
        int p = (src[e] << 10) | (et[e] << 8) | (d & 255);
        int pos = lscan[b] + atomicAdd(&lc[b], 1);
        sbuf[pos] = p;
    }
    __syncthreads();
    int tot = lscan[256];
    for (int i = t; i < tot; i += 256) {
        int lo = 0, hi = 255;
        while (lo < hi) { int mid = (lo + hi + 1) >> 1; if (lscan[mid] <= i) lo = mid; else hi = mid - 1; }
        tmp[lbase[lo] + (i - lscan[lo])] = sbuf[i];
    }
}

// ---- csr: per-bucket finalize: row_ptr, rp4 (per-rel starts), inv,
//      eidx sorted by (dst, rel) ----
__global__ __launch_bounds__(256) void csr_kernel(const int* __restrict__ tmp,
                                                  const int* __restrict__ bcnt,
                                                  int* __restrict__ row_ptr,
                                                  int4* __restrict__ rp4,
                                                  int* __restrict__ eidx,
                                                  float* __restrict__ inv, int N) {
    __shared__ int cnt4l[1024];  // counts -> in-place per-(dl,r) start offsets/cursors
    __shared__ int dscan[256];
    __shared__ int ss[256];
    __shared__ int sb[SBUF_D];
    int b = blockIdx.x, t = threadIdx.x;
    int bv = bcnt[t];
    ss[t] = bv;
    __syncthreads();
#pragma unroll
    for (int off = 1; off < 256; off <<= 1) {
        int u = (t >= off) ? ss[t - off] : 0;
        __syncthreads();
        ss[t] += u;
        __syncthreads();
    }
    __shared__ int s0s, s1s;
    if (t == b) { s0s = ss[t] - bv; s1s = ss[t]; }
    __syncthreads();
    int s0 = s0s, s1 = s1s;
    int len = s1 - s0;
    for (int i = t; i < 1024; i += 256) cnt4l[i] = 0;
    __syncthreads();
    for (int i = s0 + t; i < s1; i += 256) {
        int e = tmp[i];
        atomicAdd(&cnt4l[((e & 255) << 2) | ((e >> 8) & 3)], 1);
    }
    __syncthreads();
    int c0 = cnt4l[t * 4], c1 = cnt4l[t * 4 + 1], c2 = cnt4l[t * 4 + 2], c3 = cnt4l[t * 4 + 3];
    int deg = c0 + c1 + c2 + c3;
    ss[t] = deg;
    __syncthreads();
#pragma unroll
    for (int off = 1; off < 256; off <<= 1) {
        int u = (t >= off) ? ss[t - off] : 0;
        __syncthreads();
        ss[t] += u;
        __syncthreads();
    }
    dscan[t] = ss[t] - deg;
    int d0 = b << 8;
    int d = d0 + t;
    if (d < N) {
        inv[d * 4 + 0] = 1.0f / fmaxf((float)c0, 1.0f);
        inv[d * 4 + 1] = 1.0f / fmaxf((float)c1, 1.0f);
        inv[d * 4 + 2] = 1.0f / fmaxf((float)c2, 1.0f);
        inv[d * 4 + 3] = 1.0f / fmaxf((float)c3, 1.0f);
    }
    int base = dscan[t];
    cnt4l[t * 4] = base;
    cnt4l[t * 4 + 1] = base + c0;
    cnt4l[t * 4 + 2] = base + c0 + c1;
    cnt4l[t * 4 + 3] = base + c0 + c1 + c2;
    if (d < N) {
        row_ptr[d] = s0 + base;
        rp4[d] = make_int4(s0 + base, s0 + base + c0, s0 + base + c0 + c1,
                           s0 + base + c0 + c1 + c2);
    }
    __syncthreads();
    if (len <= SBUF_D) {
        for (int i = s0 + t; i < s1; i += 256) {
            int e = tmp[i];
            int key = ((e & 255) << 2) | ((e >> 8) & 3);
            int pos = atomicAdd(&cnt4l[key], 1);
            sb[pos] = ((e >> 10) << 2) | ((e >> 8) & 3);  // (src<<2)|et
        }
        __syncthreads();
        for (int i = t; i < len; i += 256) eidx[s0 + i] = sb[i];
    } else {
        for (int i = s0 + t; i < s1; i += 256) {
            int e = tmp[i];
            int key = ((e & 255) << 2) | ((e >> 8) & 3);
            int pos = atomicAdd(&cnt4l[key], 1);
            eidx[s0 + pos] = ((e >> 10) << 2) | ((e >> 8) & 3);
        }
    }
}

// ---- fused layer: 2-wave cooperative register-Y gather + MFMA ----
// Block = 128 thr = 2 waves over the same 16 nodes. Wave w gathers half of
// each relation segment; wave1 ships bf16 partials via LDS (frag-major,
// lane-consecutive 16B = conflict-free) and exits; wave0 sums+scales+MFMA.
__global__ __launch_bounds__(128) void layer_kernel(const int* __restrict__ row_ptr,
                                                    const int4* __restrict__ rp4,
                                                    const int* __restrict__ eidx,
                                                    const short* __restrict__ Xb,
                                                    const float* __restrict__ inv,
                                                    const short* __restrict__ Wt,
                                                    const float* __restrict__ bias,
                                                    short* __restrict__ out, int n) {
    __shared__ short part[8 * 64 * 8];  // frag f, lane l -> 16B at (f*64+l)*8
    const int t = threadIdx.x;
    const int wvid = t >> 6;
    const int l = t & 63;
    const int m = l & 15;
    const int quad = l >> 4;
    const int node = blockIdx.x * 16 + m;
    const bool valid = node < n;

    float accL[4][8], accH[4][8];
#pragma unroll
    for (int r = 0; r < 4; ++r)
#pragma unroll
        for (int j = 0; j < 8; ++j) { accL[r][j] = 0.f; accH[r][j] = 0.f; }

    int seg[5] = {0, 0, 0, 0, 0};
    float4 iv = make_float4(0.f, 0.f, 0.f, 0.f);
    if (valid) {
        int4 r4 = rp4[node];
        seg[0] = r4.x; seg[1] = r4.y; seg[2] = r4.z; seg[3] = r4.w;
        seg[4] = row_ptr[node + 1];
        iv = *(const float4*)&inv[node * 4];
    }
    const short* xbq = Xb + quad * 8;

#define GATHER(RIDX)                                                          \
    {                                                                         \
        const int slen = seg[RIDX + 1] - seg[RIDX];                           \
        int k = seg[RIDX] + ((slen * wvid) >> 1);                             \
        const int k1 = seg[RIDX] + ((slen * (wvid + 1)) >> 1);                \
        for (; k + 1 < k1; k += 2) {                                          \
            int p0 = eidx[k], p1 = eidx[k + 1];                               \
            const short* a0p = xbq + (size_t)(p0 >> 2) * 64;                  \
            const short* a1p = xbq + (size_t)(p1 >> 2) * 64;                  \
            frag_ab x0l = *(const frag_ab*)a0p;                               \
            frag_ab x0h = *(const frag_ab*)(a0p + 32);                        \
            frag_ab x1l = *(const frag_ab*)a1p;                               \
            frag_ab x1h = *(const frag_ab*)(a1p + 32);                        \
            _Pragma("unroll") for (int j = 0; j < 8; ++j) {                   \
                accL[RIDX][j] += bf2f(x0l[j]) + bf2f(x1l[j]);                 \
                accH[RIDX][j] += bf2f(x0h[j]) + bf2f(x1h[j]);                 \
            }                                                                 \
        }                                                                     \
        if (k < k1) {                                                         \
            int p0 = eidx[k];                                                 \
            const short* a0p = xbq + (size_t)(p0 >> 2) * 64;                  \
            frag_ab x0l = *(const frag_ab*)a0p;                               \
            frag_ab x0h = *(const frag_ab*)(a0p + 32);                        \
            _Pragma("unroll") for (int j = 0; j < 8; ++j) {                   \
                accL[RIDX][j] += bf2f(x0l[j]);                                \
                accH[RIDX][j] += bf2f(x0h[j]);                                \
            }                                                                 \
        }                                                                     \
    }

    GATHER(0)
    GATHER(1)
    GATHER(2)
    GATHER(3)
#undef GATHER

    if (wvid == 1) {
        // ship partials: frag 2r = accL[r], frag 2r+1 = accH[r]
#pragma unroll
        for (int r = 0; r < 4; ++r) {
            frag_ab pl, ph;
#pragma unroll
            for (int j = 0; j < 8; ++j) { pl[j] = f2bf(accL[r][j]); ph[j] = f2bf(accH[r][j]); }
            *(frag_ab*)&part[((2 * r) * 64 + l) * 8] = pl;
            *(frag_ab*)&part[((2 * r + 1) * 64 + l) * 8] = ph;
        }
    }
    __syncthreads();
    if (wvid == 1) return;

    // wave 0: add partner partials
#pragma unroll
    for (int r = 0; r < 4; ++r) {
        frag_ab pl = *(const frag_ab*)&part[((2 * r) * 64 + l) * 8];
        frag_ab ph = *(const frag_ab*)&part[((2 * r + 1) * 64 + l) * 8];
#pragma unroll
        for (int j = 0; j < 8; ++j) {
            accL[r][j] += bf2f(pl[j]);
            accH[r][j] += bf2f(ph[j]);
        }
    }

    // build A-frags: a[0..1] = X row; a[2+2r], a[3+2r] = Y_r * inv_r
    frag_ab a[10];
#pragma unroll
    for (int f = 0; f < 10; ++f) a[f] = frag_ab{};
    if (valid) {
        const short* xr = Xb + (size_t)node * 64 + quad * 8;
        a[0] = *(const frag_ab*)xr;
        a[1] = *(const frag_ab*)(xr + 32);
    }
    {
        float s0 = iv.x, s1 = iv.y, s2 = iv.z, s3 = iv.w;
#pragma unroll
        for (int j = 0; j < 8; ++j) {
            a[2][j] = f2bf(accL[0][j] * s0); a[3][j] = f2bf(accH[0][j] * s0);
            a[4][j] = f2bf(accL[1][j] * s1); a[5][j] = f2bf(accH[1][j] * s1);
            a[6][j] = f2bf(accL[2][j] * s2); a[7][j] = f2bf(accH[2][j] * s2);
            a[8][j] = f2bf(accL[3][j] * s3); a[9][j] = f2bf(accH[3][j] * s3);
        }
    }

    const int nrow_base = blockIdx.x * 16 + quad * 4;
#pragma unroll
    for (int ct = 0; ct < 4; ++ct) {
        const short* bp = Wt + (size_t)(ct * 16 + m) * KK + quad * 8;
        frag_cd acc = {0.f, 0.f, 0.f, 0.f};
#pragma unroll
        for (int f = 0; f < 10; ++f) {
            frag_ab bf = *(const frag_ab*)(bp + f * 32);
            acc = __builtin_amdgcn_mfma_f32_16x16x32_bf16(a[f], bf, acc, 0, 0, 0);
        }
        int col = ct * 16 + m;
        float bv = bias[col];
#pragma unroll
        for (int r = 0; r < 4; ++r) {
            int nr = nrow_base + r;
            if (nr < n) out[(size_t)nr * 64 + col] = f2bf(fmaxf(acc[r] + bv, 0.f));
        }
    }
}

// ---- pool (segmented) + classifier ----
__global__ __launch_bounds__(256) void pool_cls_kernel(const short* __restrict__ h2,
                                                       const int* __restrict__ gstart,
                                                       const float* __restrict__ w,
                                                       const float* __restrict__ b,
                                                       float* __restrict__ out) {
    __shared__ float red[4][64];
    const int g = blockIdx.x;
    const int t = threadIdx.x;
    const int h = t & 63;
    const int wv = t >> 6;
    const int s = gstart[g], e = gstart[g + 1];

    float acc = 0.f;
    for (int i = s + wv; i < e; i += 4) acc += bf2f(h2[(size_t)i * 64 + h]);
    red[wv][h] = acc;
    __syncthreads();
    if (wv == 0) {
        float sum = red[0][h] + red[1][h] + red[2][h] + red[3][h];
        red[0][h] = sum / fmaxf((float)(e - s), 1.0f);
    }
    __syncthreads();
    if (t < 4) {
        float sres = 0.f;
#pragma unroll 8
        for (int hh = 0; hh < 64; ++hh) sres += red[0][hh] * w[hh * 4 + t];
        out[g * 4 + t] = sres + b[t];
    }
}

extern "C" void kernel_launch(void* const* d_in, const int* in_sizes, int n_in,
                              void* d_out, int out_size, void* d_ws, size_t ws_size,
                              hipStream_t stream) {
    const float* x        = (const float*)d_in[0];
    const int* edge_index = (const int*)d_in[1];
    const int* edge_type  = (const int*)d_in[2];
    const int* batch      = (const int*)d_in[3];
    const float* basis1 = (const float*)d_in[4];
    const float* comp1  = (const float*)d_in[5];
    const float* root1  = (const float*)d_in[6];
    const float* bias1  = (const float*)d_in[7];
    const float* basis2 = (const float*)d_in[8];
    const float* comp2  = (const float*)d_in[9];
    const float* root2  = (const float*)d_in[10];
    const float* bias2  = (const float*)d_in[11];
    const float* clas_w = (const float*)d_in[12];
    const float* clas_b = (const float*)d_in[13];

    const int N = in_sizes[0] / 64;
    const int E = in_sizes[2];
    const int G = out_size / 4;
    const int* src = edge_index;
    const int* dst = edge_index + E;
    const int NBUCK = (N + 255) >> 8;

    char* base = (char*)d_ws;
    size_t off = 0;
    auto carve = [&](size_t bytes) { void* p = base + off; off = (off + bytes + 15) & ~(size_t)15; return p; };
    int*   bcnt    = (int*)carve(sizeof(int) * 256);
    int*   cur0    = (int*)carve(sizeof(int) * 256);
    int*   row_ptr = (int*)carve(sizeof(int) * ((size_t)N + 1));
    int4*  rp4     = (int4*)carve(sizeof(int4) * (size_t)N);
    int*   gstart  = (int*)carve(sizeof(int) * ((size_t)G + 1));
    int*   eidx    = (int*)carve(sizeof(int) * (size_t)E);
    int*   tmp     = (int*)carve(sizeof(int) * (size_t)E);
    float* inv     = (float*)carve(sizeof(float) * (size_t)N * RR);
    short* W1t     = (short*)carve(sizeof(short) * LWN);
    short* W2t     = (short*)carve(sizeof(short) * LWN);
    short* Xb1     = (short*)carve(sizeof(short) * (size_t)N * 64);
    short* H1      = (short*)carve(sizeof(short) * (size_t)N * 64);
    short* H2      = (short*)carve(sizeof(short) * (size_t)N * 64);

    const int nb  = (N + 255) / 256;
    const int ebl = (E + EPB - 1) / EPB;
    const int wbl = (2 * LWN + 255) / 256;
    const int cvb = (N * 64 / 4 + 255) / 256;
    const int prep_blocks = ebl + wbl + nb + cvb;

    hipMemsetAsync(bcnt, 0, sizeof(int) * 512, stream);  // bcnt + cur0

    prep_kernel<<<prep_blocks, 256, 0, stream>>>(
        dst, E, NBUCK, bcnt,
        basis1, comp1, root1, basis2, comp2, root2, W1t, W2t,
        batch, gstart, N, G, row_ptr, x, Xb1, ebl, wbl, nb);
    bin_kernel<<<ebl, 256, 0, stream>>>(src, dst, edge_type, bcnt, cur0, tmp, E);
    csr_kernel<<<NBUCK, 256, 0, stream>>>(tmp, bcnt, row_ptr, rp4, eidx, inv, N);

    const int layer_blocks = (N + 15) / 16;

    layer_kernel<<<layer_blocks, 128, 0, stream>>>(row_ptr, rp4, eidx, Xb1, inv, W1t, bias1, H1, N);
    layer_kernel<<<layer_blocks, 128, 0, stream>>>(row_ptr, rp4, eidx, H1, inv, W2t, bias2, H2, N);

    pool_cls_kernel<<<G, 256, 0, stream>>>(H2, gstart, clas_w, clas_b, (float*)d_out);
}